// Round 3
// baseline (1170.396 us; speedup 1.0000x reference)
//
#include <hip/hip_runtime.h>
#include <stdint.h>

typedef unsigned short u16;
typedef __attribute__((ext_vector_type(4))) float f32x4;
typedef __attribute__((ext_vector_type(8))) short bf16x8;

#define MFMA16(a, b, c) __builtin_amdgcn_mfma_f32_16x16x32_bf16((a), (b), (c), 0, 0, 0)

__device__ __forceinline__ float bu2f(u16 u) {
  union { unsigned int i; float f; } c; c.i = ((unsigned int)u) << 16; return c.f;
}
__device__ __forceinline__ u16 f2bu(float f) {
  union { float f; unsigned int i; } c; c.f = f;
  unsigned int x = c.i;
  return (u16)((x + 0x7FFFu + ((x >> 16) & 1u)) >> 16);  // RNE
}

typedef const __attribute__((address_space(1))) void GVoid;
typedef __attribute__((address_space(3))) void LVoid;

__device__ __forceinline__ void gl_lds16(const void* g, void* l) {
  __builtin_amdgcn_global_load_lds((GVoid*)(uintptr_t)g, (LVoid*)(uintptr_t)l, 16, 0, 0);
}

// ---------------- fp32 -> bf16 weight conversion (8 elems/thread) ----------------
struct __align__(16) bf8pack { u16 v[8]; };
struct __align__(8) bf4pack { u16 v[4]; };

__global__ __launch_bounds__(256) void f2b_kernel(const float* __restrict__ in,
                                                  u16* __restrict__ out, int n8) {
  int i = blockIdx.x * 256 + threadIdx.x;
  if (i >= n8) return;
  const f32x4* in4 = (const f32x4*)in;
  f32x4 a = in4[i * 2], b = in4[i * 2 + 1];
  bf8pack p;
  p.v[0] = f2bu(a[0]); p.v[1] = f2bu(a[1]); p.v[2] = f2bu(a[2]); p.v[3] = f2bu(a[3]);
  p.v[4] = f2bu(b[0]); p.v[5] = f2bu(b[1]); p.v[6] = f2bu(b[2]); p.v[7] = f2bu(b[3]);
  ((bf8pack*)out)[i] = p;
}

// ---------------- fp32 W[N][1024] -> [hi|hi|lo] bf16 [N][3072] (B-side split) ----------------
__global__ __launch_bounds__(256) void wsplit3_kernel(const float* __restrict__ w,
                                                      u16* __restrict__ out) {
  int i = blockIdx.x * 256 + threadIdx.x;  // 8-elem group
  int n = i >> 7, k0 = (i & 127) * 8;
  const f32x4* p = (const f32x4*)(w + (size_t)n * 1024 + k0);
  f32x4 a = p[0], b = p[1];
  float f[8] = {a[0], a[1], a[2], a[3], b[0], b[1], b[2], b[3]};
  bf8pack hi, lo;
#pragma unroll
  for (int t = 0; t < 8; ++t) {
    hi.v[t] = f2bu(f[t]);
    lo.v[t] = f2bu(f[t] - bu2f(hi.v[t]));
  }
  u16* o = out + (size_t)n * 3072 + k0;
  *(bf8pack*)o = hi;
  *(bf8pack*)(o + 1024) = hi;
  *(bf8pack*)(o + 2048) = lo;
}

// ---------------- fp32 A[4096][1024] -> [hi|lo|hi] bf16 [4096][3072] (A-side split) ----------------
__global__ __launch_bounds__(256) void asplit3_kernel(const float* __restrict__ a,
                                                      u16* __restrict__ out) {
  int i = blockIdx.x * 256 + threadIdx.x;
  int n = i >> 7, k0 = (i & 127) * 8;
  const f32x4* p = (const f32x4*)(a + (size_t)n * 1024 + k0);
  f32x4 x = p[0], y = p[1];
  float f[8] = {x[0], x[1], x[2], x[3], y[0], y[1], y[2], y[3]};
  bf8pack hi, lo;
#pragma unroll
  for (int t = 0; t < 8; ++t) {
    hi.v[t] = f2bu(f[t]);
    lo.v[t] = f2bu(f[t] - bu2f(hi.v[t]));
  }
  u16* o = out + (size_t)n * 3072 + k0;
  *(bf8pack*)o = hi;
  *(bf8pack*)(o + 1024) = lo;
  *(bf8pack*)(o + 2048) = hi;
}

// ---------------- RMSNorm fp32 row(1024) -> [hi|lo|hi] bf16 row(3072) ----------------
__global__ __launch_bounds__(256) void rmsnorm3_kernel(const float* __restrict__ x,
                                                       const float* __restrict__ w,
                                                       u16* __restrict__ out) {
  int row = blockIdx.x;
  int tid = threadIdx.x;
  const f32x4* xr = (const f32x4*)(x + (size_t)row * 1024);
  f32x4 v = xr[tid];
  float ss = v[0] * v[0] + v[1] * v[1] + v[2] * v[2] + v[3] * v[3];
#pragma unroll
  for (int off = 32; off; off >>= 1) ss += __shfl_xor(ss, off);
  __shared__ float part[4];
  if ((tid & 63) == 0) part[tid >> 6] = ss;
  __syncthreads();
  float rs = rsqrtf((part[0] + part[1] + part[2] + part[3]) * (1.0f / 1024.0f) + 1e-6f);
  const f32x4* w4 = (const f32x4*)w;
  f32x4 wv = w4[tid];
  float f[4] = {v[0] * rs * wv[0], v[1] * rs * wv[1], v[2] * rs * wv[2], v[3] * rs * wv[3]};
  bf4pack hi, lo;
#pragma unroll
  for (int t = 0; t < 4; ++t) {
    hi.v[t] = f2bu(f[t]);
    lo.v[t] = f2bu(f[t] - bu2f(hi.v[t]));
  }
  u16* o = out + (size_t)row * 3072;
  ((bf4pack*)o)[tid] = hi;
  ((bf4pack*)(o + 1024))[tid] = lo;
  ((bf4pack*)(o + 2048))[tid] = hi;
}

// ---------------- RMSNorm: fp32 row(1024) -> bf16 (MoE input, single-term) ----------------
__global__ __launch_bounds__(256) void rmsnorm_kernel(const float* __restrict__ x,
                                                      const float* __restrict__ w,
                                                      u16* __restrict__ out) {
  int row = blockIdx.x;
  int tid = threadIdx.x;
  const f32x4* xr = (const f32x4*)(x + (size_t)row * 1024);
  f32x4 v = xr[tid];
  float ss = v[0] * v[0] + v[1] * v[1] + v[2] * v[2] + v[3] * v[3];
#pragma unroll
  for (int off = 32; off; off >>= 1) ss += __shfl_xor(ss, off);
  __shared__ float part[4];
  if ((tid & 63) == 0) part[tid >> 6] = ss;
  __syncthreads();
  float rs = rsqrtf((part[0] + part[1] + part[2] + part[3]) * (1.0f / 1024.0f) + 1e-6f);
  const f32x4* w4 = (const f32x4*)w;
  f32x4 wv = w4[tid];
  bf4pack o;
  o.v[0] = f2bu(v[0] * rs * wv[0]);
  o.v[1] = f2bu(v[1] * rs * wv[1]);
  o.v[2] = f2bu(v[2] * rs * wv[2]);
  o.v[3] = f2bu(v[3] * rs * wv[3]);
  ((bf4pack*)out)[(size_t)row * 256 + tid] = o;
}

// ---------------- MFMA GEMM, C = A @ B^T, 128x128 tile, BK=64, 4 waves ----------------
// MODE 0: C f32  = acc + bias                       (qkv, split-K input)
// MODE 1: C f32  = acc + bias + resid               (out-proj + residual, split-K input)
// MODE 2: gathered A (slot_token), dual B, h = silu(acc1+b1)*(acc2+b2) -> bf16
// MODE 3: scatter: atomicAdd(out[token], (acc+bias)*slot_weight)
template <int MODE>
__global__ __launch_bounds__(256, 2) void gemm_kernel(
    const u16* __restrict__ A, const u16* __restrict__ B1g, const u16* __restrict__ B2g,
    const float* __restrict__ bias1, const float* __restrict__ bias2,
    void* __restrict__ outp, const float* __restrict__ resid, int N, int K,
    const int* __restrict__ counts, const int* __restrict__ opad,
    const int* __restrict__ slot_token, const float* __restrict__ slot_weight) {
  constexpr bool DUAL = (MODE == 2);
  const int tid = threadIdx.x;
  const int lane = tid & 63;
  const int wid = tid >> 6;
  const int wr = wid >> 1, wc = wid & 1;
  const int n0 = blockIdx.x * 128;
  const int mt = blockIdx.y;
  const int e = (MODE >= 2) ? blockIdx.z : 0;
  int m0;
  if (MODE >= 2) {
    int cnt = counts[e];
    if (mt * 128 >= cnt) return;
    m0 = opad[e] + mt * 128;
  } else {
    m0 = mt * 128;
  }
  const u16* B1 = B1g + ((MODE >= 2) ? (size_t)e * (size_t)N * (size_t)K : (size_t)0);
  const u16* B2 = DUAL ? (B2g + (size_t)e * (size_t)N * (size_t)K) : nullptr;
  const float* bb1 = bias1 + ((MODE >= 2) ? e * N : 0);
  const float* bb2 = DUAL ? (bias2 + e * N) : nullptr;

  __shared__ u16 smem[(DUAL ? 3 : 2) * 128 * 64];
  u16* As = smem;
  u16* Bs = smem + 128 * 64;
  u16* B2s = smem + 2 * 128 * 64;

  const f32x4 zero4 = {0.f, 0.f, 0.f, 0.f};
  f32x4 acc[4][4], acc2[4][4];
#pragma unroll
  for (int mi = 0; mi < 4; ++mi)
#pragma unroll
    for (int ni = 0; ni < 4; ++ni) {
      acc[mi][ni] = zero4;
      if constexpr (DUAL) acc2[mi][ni] = zero4;
    }

  const int rsel = lane & 15;
  const int ksel = lane >> 4;

  for (int k0 = 0; k0 < K; k0 += 64) {
    if (k0) __syncthreads();
#pragma unroll
    for (int i = 0; i < 4; ++i) {
      int c = tid + i * 256;
      int row = c >> 3;
      int col = (c & 7) * 8;
      size_t arow;
      if constexpr (MODE == 2) arow = (size_t)slot_token[m0 + row];
      else arow = (size_t)(m0 + row);
      gl_lds16(A + arow * (size_t)K + k0 + col, As + c * 8);
      gl_lds16(B1 + (size_t)(n0 + row) * K + k0 + col, Bs + c * 8);
      if constexpr (DUAL) gl_lds16(B2 + (size_t)(n0 + row) * K + k0 + col, B2s + c * 8);
    }
    __syncthreads();
    const u16* Aw = As + (wr * 64) * 64;
    const u16* Bw = Bs + (wc * 64) * 64;
    const u16* B2w = B2s + (wc * 64) * 64;
#pragma unroll
    for (int ks = 0; ks < 2; ++ks) {
      int ko = ks * 32 + ksel * 8;
      bf16x8 a[4], b[4];
#pragma unroll
      for (int mi = 0; mi < 4; ++mi) a[mi] = *(const bf16x8*)(Aw + (mi * 16 + rsel) * 64 + ko);
#pragma unroll
      for (int ni = 0; ni < 4; ++ni) b[ni] = *(const bf16x8*)(Bw + (ni * 16 + rsel) * 64 + ko);
#pragma unroll
      for (int mi = 0; mi < 4; ++mi)
#pragma unroll
        for (int ni = 0; ni < 4; ++ni) acc[mi][ni] = MFMA16(a[mi], b[ni], acc[mi][ni]);
      if constexpr (DUAL) {
        bf16x8 b2[4];
#pragma unroll
        for (int ni = 0; ni < 4; ++ni) b2[ni] = *(const bf16x8*)(B2w + (ni * 16 + rsel) * 64 + ko);
#pragma unroll
        for (int mi = 0; mi < 4; ++mi)
#pragma unroll
          for (int ni = 0; ni < 4; ++ni) acc2[mi][ni] = MFMA16(a[mi], b2[ni], acc2[mi][ni]);
      }
    }
  }

  // epilogue: C row = (lane>>4)*4 + j, col = lane&15  [m89-verified layout]
#pragma unroll
  for (int mi = 0; mi < 4; ++mi) {
#pragma unroll
    for (int j = 0; j < 4; ++j) {
      int gm = m0 + wr * 64 + mi * 16 + ksel * 4 + j;
#pragma unroll
      for (int ni = 0; ni < 4; ++ni) {
        int gn = n0 + wc * 64 + ni * 16 + rsel;
        float v = acc[mi][ni][j];
        if constexpr (MODE == 0) {
          ((float*)outp)[(size_t)gm * N + gn] = v + bb1[gn];
        } else if constexpr (MODE == 1) {
          ((float*)outp)[(size_t)gm * N + gn] = v + bb1[gn] + resid[(size_t)gm * N + gn];
        } else if constexpr (MODE == 2) {
          float v1 = v + bb1[gn];
          float v2 = acc2[mi][ni][j] + bb2[gn];
          float hv = (v1 / (1.f + __expf(-v1))) * v2;  // silu(v1)*v2
          ((u16*)outp)[(size_t)gm * N + gn] = f2bu(hv);
        } else {
          int tok = slot_token[gm];
          float w = slot_weight[gm];
          atomicAdd(((float*)outp) + (size_t)tok * N + gn, (v + bb1[gn]) * w);
        }
      }
    }
  }
}

// ---------------- RoPE (double-precision angles) + split qkv -> hi/lo planes ----------------
__global__ __launch_bounds__(256) void rope_split_kernel(
    const float* __restrict__ qkv, u16* __restrict__ qhp, u16* __restrict__ qlp,
    u16* __restrict__ khp, u16* __restrict__ klp, u16* __restrict__ vhp,
    u16* __restrict__ vlp) {
  int idx = blockIdx.x * 256 + threadIdx.x;  // [bh][s][hd] flat, 4,194,304
  int hd = idx & 63;
  int s = (idx >> 6) & 2047;
  int bh = idx >> 17;
  int b = bh >> 4, h = bh & 15;
  size_t base = (size_t)(b * 2048 + s) * 3072 + (size_t)h * 64;
  float qv = qkv[base + hd];
  float qp = qkv[base + (hd ^ 32)];
  float kv = qkv[base + 1024 + hd];
  float kp = qkv[base + 1024 + (hd ^ 32)];
  float vv = qkv[base + 2048 + hd];
  int j = hd & 31;
  // double-precision angle: fp32 angle has ulp ~1.2e-4 at s=2047 -> would flip routing
  double invf = exp((double)j * (-9.210340371976184 / 32.0));  // 10000^(-j/32)
  double ang = (double)s * invf;
  const double twopi = 6.283185307179586;
  double r = ang - twopi * floor(ang / twopi);
  float sn, c;
  sincosf((float)r, &sn, &c);
  float qo = (hd < 32) ? (qv * c - qp * sn) : (qv * c + qp * sn);
  float ko = (hd < 32) ? (kv * c - kp * sn) : (kv * c + kp * sn);
  u16 qh = f2bu(qo), kh = f2bu(ko), vh = f2bu(vv);
  qhp[idx] = qh; qlp[idx] = f2bu(qo - bu2f(qh));
  khp[idx] = kh; klp[idx] = f2bu(ko - bu2f(kh));
  vhp[idx] = vh; vlp[idx] = f2bu(vv - bu2f(vh));
}

// ---------------- flash attention, split-precision (hi/lo) Q,K,V,P ----------------
__global__ __launch_bounds__(256, 2) void flash_kernel(
    const u16* __restrict__ qhp, const u16* __restrict__ qlp, const u16* __restrict__ khp,
    const u16* __restrict__ klp, const u16* __restrict__ vhp, const u16* __restrict__ vlp,
    float* __restrict__ attn_out) {
  int qblk = blockIdx.x, bh = blockIdx.y;
  int tid = threadIdx.x, lane = tid & 63, wid = tid >> 6;
  const int rsel = lane & 15, ksel = lane >> 4;
  const size_t bhbase = (size_t)bh * 2048 * 64;
  __shared__ u16 Ksh[64 * 64], Ksl[64 * 64];
  __shared__ u16 Vsh[64 * 64], Vsl[64 * 64];  // transposed: [hd][kv]
  __shared__ u16 Psh[4][16 * 64], Psl[4][16 * 64];
  int qr0 = qblk * 64 + wid * 16;
  bf16x8 qfh[2], qfl[2];
#pragma unroll
  for (int ks = 0; ks < 2; ++ks) {
    size_t qoff = bhbase + (size_t)(qr0 + rsel) * 64 + ks * 32 + ksel * 8;
    qfh[ks] = *(const bf16x8*)(qhp + qoff);
    qfl[ks] = *(const bf16x8*)(qlp + qoff);
  }

  const f32x4 zero4 = {0.f, 0.f, 0.f, 0.f};
  f32x4 po[4];
  float m_i[4], l_i[4];
#pragma unroll
  for (int i = 0; i < 4; ++i) { po[i] = zero4; m_i[i] = -1e30f; l_i[i] = 0.f; }

  for (int kv0 = 0; kv0 < 2048; kv0 += 64) {
    __syncthreads();
#pragma unroll
    for (int i = 0; i < 2; ++i) {  // K tiles: linear copies
      int c = tid + i * 256;
      gl_lds16(khp + bhbase + (size_t)kv0 * 64 + c * 8, Ksh + c * 8);
      gl_lds16(klp + bhbase + (size_t)kv0 * 64 + c * 8, Ksl + c * 8);
    }
#pragma unroll
    for (int i = 0; i < 2; ++i) {  // V tiles transposed
      int c = tid + i * 256;
      int r = c >> 3, col0 = (c & 7) * 8;
      bf16x8 a = *(const bf16x8*)(vhp + bhbase + (size_t)(kv0 + r) * 64 + col0);
      bf16x8 bl = *(const bf16x8*)(vlp + bhbase + (size_t)(kv0 + r) * 64 + col0);
#pragma unroll
      for (int jj = 0; jj < 8; ++jj) {
        Vsh[(col0 + jj) * 64 + r] = (u16)a[jj];
        Vsl[(col0 + jj) * 64 + r] = (u16)bl[jj];
      }
    }
    __syncthreads();

    f32x4 sa[4] = {zero4, zero4, zero4, zero4};
#pragma unroll
    for (int ks = 0; ks < 2; ++ks) {
      int ko = ks * 32 + ksel * 8;
#pragma unroll
      for (int ni = 0; ni < 4; ++ni) {
        bf16x8 kbh = *(const bf16x8*)(Ksh + (ni * 16 + rsel) * 64 + ko);
        bf16x8 kbl = *(const bf16x8*)(Ksl + (ni * 16 + rsel) * 64 + ko);
        sa[ni] = MFMA16(qfh[ks], kbh, sa[ni]);
        sa[ni] = MFMA16(qfl[ks], kbh, sa[ni]);
        sa[ni] = MFMA16(qfh[ks], kbl, sa[ni]);
      }
    }
    const float scale = 0.125f;
    float corr[4];
#pragma unroll
    for (int i = 0; i < 4; ++i) {
      float t = sa[0][i] * scale;
      t = fmaxf(t, sa[1][i] * scale);
      t = fmaxf(t, sa[2][i] * scale);
      t = fmaxf(t, sa[3][i] * scale);
#pragma unroll
      for (int off = 1; off < 16; off <<= 1) t = fmaxf(t, __shfl_xor(t, off));
      float mn = fmaxf(m_i[i], t);
      corr[i] = __expf(m_i[i] - mn);
      m_i[i] = mn;
    }
    float rsum[4] = {0.f, 0.f, 0.f, 0.f};
#pragma unroll
    for (int ni = 0; ni < 4; ++ni)
#pragma unroll
      for (int i = 0; i < 4; ++i) {
        float p = __expf(sa[ni][i] * scale - m_i[i]);
        rsum[i] += p;
        u16 ph = f2bu(p);
        Psh[wid][(ksel * 4 + i) * 64 + ni * 16 + rsel] = ph;
        Psl[wid][(ksel * 4 + i) * 64 + ni * 16 + rsel] = f2bu(p - bu2f(ph));
      }
#pragma unroll
    for (int i = 0; i < 4; ++i) {
      float t = rsum[i];
#pragma unroll
      for (int off = 1; off < 16; off <<= 1) t += __shfl_xor(t, off);
      l_i[i] = l_i[i] * corr[i] + t;
    }
#pragma unroll
    for (int nh = 0; nh < 4; ++nh)
#pragma unroll
      for (int i = 0; i < 4; ++i) po[nh][i] *= corr[i];
    __syncthreads();  // P writes visible (safe barrier; drains lgkm)
#pragma unroll
    for (int ks = 0; ks < 2; ++ks) {
      int ko = ks * 32 + ksel * 8;
      bf16x8 pfh = *(const bf16x8*)(&Psh[wid][rsel * 64 + ko]);
      bf16x8 pfl = *(const bf16x8*)(&Psl[wid][rsel * 64 + ko]);
#pragma unroll
      for (int nh = 0; nh < 4; ++nh) {
        bf16x8 vbh = *(const bf16x8*)(Vsh + (nh * 16 + rsel) * 64 + ko);
        bf16x8 vbl = *(const bf16x8*)(Vsl + (nh * 16 + rsel) * 64 + ko);
        po[nh] = MFMA16(pfh, vbh, po[nh]);
        po[nh] = MFMA16(pfl, vbh, po[nh]);
        po[nh] = MFMA16(pfh, vbl, po[nh]);
      }
    }
  }
  int b = bh >> 4, h = bh & 15;
#pragma unroll
  for (int i = 0; i < 4; ++i) {
    float inv = 1.0f / l_i[i];
    int row = qr0 + ksel * 4 + i;
    size_t obase = (size_t)(b * 2048 + row) * 1024 + (size_t)h * 64;
#pragma unroll
    for (int nh = 0; nh < 4; ++nh) attn_out[obase + nh * 16 + rsel] = po[nh][i] * inv;
  }
}

// ---------------- gate: fp32 rmsnorm + logits + top2 (1 wave / token) ----------------
__global__ __launch_bounds__(256) void gate_kernel(const float* __restrict__ xres,
                                                   const float* __restrict__ n2w,
                                                   const float* __restrict__ gw,
                                                   int* __restrict__ tok_e, float* __restrict__ tok_w,
                                                   int* __restrict__ counts) {
  int token = blockIdx.x * 4 + (threadIdx.x >> 6);
  int lane = threadIdx.x & 63;
  const f32x4* xr = (const f32x4*)(xres + (size_t)token * 1024);
  f32x4 xv[4];
  float ss = 0.f;
#pragma unroll
  for (int i = 0; i < 4; ++i) {
    xv[i] = xr[lane * 4 + i];
    ss += xv[i][0] * xv[i][0] + xv[i][1] * xv[i][1] + xv[i][2] * xv[i][2] + xv[i][3] * xv[i][3];
  }
#pragma unroll
  for (int off = 32; off; off >>= 1) ss += __shfl_xor(ss, off);
  float rs = rsqrtf(ss * (1.0f / 1024.0f) + 1e-6f);
  const f32x4* w4 = (const f32x4*)n2w;
#pragma unroll
  for (int i = 0; i < 4; ++i) {
    f32x4 wv = w4[lane * 4 + i];
    xv[i][0] *= rs * wv[0]; xv[i][1] *= rs * wv[1]; xv[i][2] *= rs * wv[2]; xv[i][3] *= rs * wv[3];
  }
  float lg[8];
#pragma unroll
  for (int ee = 0; ee < 8; ++ee) {
    const f32x4* g4 = (const f32x4*)(gw + ee * 1024);
    float a = 0.f;
#pragma unroll
    for (int i = 0; i < 4; ++i) {
      f32x4 g = g4[lane * 4 + i];
      a += xv[i][0] * g[0] + xv[i][1] * g[1] + xv[i][2] * g[2] + xv[i][3] * g[3];
    }
#pragma unroll
    for (int off = 32; off; off >>= 1) a += __shfl_xor(a, off);
    lg[ee] = a;
  }
  if (lane == 0) {
    int i1 = 0; float v1 = lg[0];
#pragma unroll
    for (int ee = 1; ee < 8; ++ee) if (lg[ee] > v1) { v1 = lg[ee]; i1 = ee; }
    int i2 = -1; float v2 = -3e38f;
#pragma unroll
    for (int ee = 0; ee < 8; ++ee) if (ee != i1 && lg[ee] > v2) { v2 = lg[ee]; i2 = ee; }
    float s2 = 1.f / (1.f + __expf(v1 - v2));
    float s1 = 1.f - s2;
    tok_e[token * 2] = i1; tok_e[token * 2 + 1] = i2;
    tok_w[token * 2] = s1; tok_w[token * 2 + 1] = s2;
    atomicAdd(&counts[i1], 1); atomicAdd(&counts[i2], 1);
  }
}

__global__ void init_kernel(int* counts, int* cursor, int* slot_token, float* slot_weight) {
  int i = blockIdx.x * 256 + threadIdx.x;
  if (i < 8) { counts[i] = 0; cursor[i] = 0; }
  if (i < 10240) { slot_token[i] = 0; slot_weight[i] = 0.f; }
}

__global__ void scan_kernel(const int* counts, int* opad) {
  if (threadIdx.x == 0) {
    int off = 0;
    for (int e = 0; e < 8; ++e) { opad[e] = off; off += ((counts[e] + 127) >> 7) << 7; }
  }
}

__global__ __launch_bounds__(256) void assign_kernel(const int* __restrict__ tok_e,
                                                     const float* __restrict__ tok_w,
                                                     const int* __restrict__ opad, int* cursor,
                                                     int* __restrict__ slot_token,
                                                     float* __restrict__ slot_weight) {
  int t = blockIdx.x * 256 + threadIdx.x;
#pragma unroll
  for (int j = 0; j < 2; ++j) {
    int e = tok_e[t * 2 + j];
    int pos = atomicAdd(&cursor[e], 1);
    slot_token[opad[e] + pos] = t;
    slot_weight[opad[e] + pos] = tok_w[t * 2 + j];
  }
}

extern "C" void kernel_launch(void* const* d_in, const int* in_sizes, int n_in, void* d_out,
                              int out_size, void* d_ws, size_t ws_size, hipStream_t stream) {
  const float* x = (const float*)d_in[0];
  const float* n1w = (const float*)d_in[1];
  const float* n2w = (const float*)d_in[2];
  const float* qkv_w = (const float*)d_in[3];
  const float* qkv_b = (const float*)d_in[4];
  const float* out_w = (const float*)d_in[5];
  const float* out_b = (const float*)d_in[6];
  const float* gate_w = (const float*)d_in[7];
  const float* w1 = (const float*)d_in[8];
  const float* b1 = (const float*)d_in[9];
  const float* w2 = (const float*)d_in[10];
  const float* b2 = (const float*)d_in[11];
  const float* w3 = (const float*)d_in[12];
  const float* b3 = (const float*)d_in[13];
  float* out = (float*)d_out;

  const size_t MB = 1024 * 1024;
  char* ws = (char*)d_ws;
  // R0 (96MB): phase1: qkvbuf f32 (48M) + 6 q/k/v planes (8M each); phase2: w1b/w2b/w3b (32M each)
  char* R0 = ws;
  // R1 (44MB): phase1: xn3 (24M) + qkvw3 (18M); then attn3 (24M) overlays xn3; then hbuf (38M)
  char* R1 = ws + 96 * MB;
  // R2 (16MB): attnout f32 (16M); then xn_moe bf16 (8M)
  char* R2 = R1 + 44 * MB;
  // R3 (8MB): outw3 (6M)
  char* R3 = R2 + 16 * MB;
  // R4 (1MB): routing metadata
  char* R4 = R3 + 8 * MB;
  if ((size_t)(165 * MB) > ws_size) return;  // signature: absmax == max|ref|

  float* qkvbuf = (float*)R0;
  u16* qhp = (u16*)(R0 + 48 * MB);
  u16* qlp = (u16*)(R0 + 56 * MB);
  u16* khp = (u16*)(R0 + 64 * MB);
  u16* klp = (u16*)(R0 + 72 * MB);
  u16* vhp = (u16*)(R0 + 80 * MB);
  u16* vlp = (u16*)(R0 + 88 * MB);
  u16* w1b = (u16*)R0;
  u16* w2b = (u16*)(R0 + 32 * MB);
  u16* w3b = (u16*)(R0 + 64 * MB);
  u16* xn3 = (u16*)R1;
  u16* qkvw3 = (u16*)(R1 + 24 * MB);
  u16* attn3 = (u16*)R1;
  u16* hbuf = (u16*)R1;
  float* attnout = (float*)R2;
  u16* xn_moe = (u16*)R2;
  u16* outw3 = (u16*)R3;
  int* tok_e = (int*)R4;
  float* tok_w = (float*)(R4 + 64 * 1024);
  int* counts = (int*)(R4 + 128 * 1024);
  int* cursor = (int*)(R4 + 132 * 1024);
  int* opad = (int*)(R4 + 136 * 1024);
  int* slot_token = (int*)(R4 + 192 * 1024);
  float* slot_weight = (float*)(R4 + 256 * 1024);

  // ---- attention path (split precision) ----
  rmsnorm3_kernel<<<4096, 256, 0, stream>>>(x, n1w, xn3);
  wsplit3_kernel<<<1536, 256, 0, stream>>>(qkv_w, qkvw3);
  wsplit3_kernel<<<512, 256, 0, stream>>>(out_w, outw3);
  gemm_kernel<0><<<dim3(24, 32, 1), 256, 0, stream>>>(xn3, qkvw3, nullptr, qkv_b, nullptr, qkvbuf,
                                                      nullptr, 3072, 3072, nullptr, nullptr,
                                                      nullptr, nullptr);
  rope_split_kernel<<<16384, 256, 0, stream>>>(qkvbuf, qhp, qlp, khp, klp, vhp, vlp);
  flash_kernel<<<dim3(32, 32, 1), 256, 0, stream>>>(qhp, qlp, khp, klp, vhp, vlp, attnout);
  // MoE weight converts (R0 planes dead after flash)
  f2b_kernel<<<8192, 256, 0, stream>>>(w1, w1b, 2097152);
  f2b_kernel<<<8192, 256, 0, stream>>>(w2, w2b, 2097152);
  f2b_kernel<<<8192, 256, 0, stream>>>(w3, w3b, 2097152);
  asplit3_kernel<<<2048, 256, 0, stream>>>(attnout, attn3);
  gemm_kernel<1><<<dim3(8, 32, 1), 256, 0, stream>>>(attn3, outw3, nullptr, out_b, nullptr, out, x,
                                                     1024, 3072, nullptr, nullptr, nullptr, nullptr);
  // ---- MoE path (bf16) ----
  rmsnorm_kernel<<<4096, 256, 0, stream>>>(out, n2w, xn_moe);
  init_kernel<<<40, 256, 0, stream>>>(counts, cursor, slot_token, slot_weight);
  gate_kernel<<<1024, 256, 0, stream>>>(out, n2w, gate_w, tok_e, tok_w, counts);
  scan_kernel<<<1, 64, 0, stream>>>(counts, opad);
  assign_kernel<<<16, 256, 0, stream>>>(tok_e, tok_w, opad, cursor, slot_token, slot_weight);
  gemm_kernel<2><<<dim3(16, 32, 8), 256, 0, stream>>>(xn_moe, w1b, w2b, b1, b2, hbuf, nullptr, 2048,
                                                      1024, counts, opad, slot_token, slot_weight);
  gemm_kernel<3><<<dim3(8, 32, 8), 256, 0, stream>>>(hbuf, w3b, nullptr, b3, nullptr, out, nullptr,
                                                     1024, 2048, counts, opad, slot_token,
                                                     slot_weight);
}

// Round 4
// 1089.172 us; speedup vs baseline: 1.0746x; 1.0746x over previous
//
#include <hip/hip_runtime.h>
#include <stdint.h>

typedef unsigned short u16;
typedef __attribute__((ext_vector_type(4))) float f32x4;
typedef __attribute__((ext_vector_type(8))) short bf16x8;

#define MFMA16(a, b, c) __builtin_amdgcn_mfma_f32_16x16x32_bf16((a), (b), (c), 0, 0, 0)

__device__ __forceinline__ float bu2f(u16 u) {
  union { unsigned int i; float f; } c; c.i = ((unsigned int)u) << 16; return c.f;
}
__device__ __forceinline__ u16 f2bu(float f) {
  union { float f; unsigned int i; } c; c.f = f;
  unsigned int x = c.i;
  return (u16)((x + 0x7FFFu + ((x >> 16) & 1u)) >> 16);  // RNE
}

typedef const __attribute__((address_space(1))) void GVoid;
typedef __attribute__((address_space(3))) void LVoid;

__device__ __forceinline__ void gl_lds16(const void* g, void* l) {
  __builtin_amdgcn_global_load_lds((GVoid*)(uintptr_t)g, (LVoid*)(uintptr_t)l, 16, 0, 0);
}

// LDS XOR-swizzle for 128B-row tiles (u16-index units, flips bits 3-5).
// row&7 spreads read-side lanes (rows vary in low bits); row>>3 spreads
// V-transpose write-side lanes (rows vary in bits 3-5). Involution.
__device__ __forceinline__ int swz(int row) { return ((row ^ (row >> 3)) & 7) << 3; }

// ---------------- fp32 -> bf16 weight conversion (8 elems/thread) ----------------
struct __align__(16) bf8pack { u16 v[8]; };
struct __align__(8) bf4pack { u16 v[4]; };

__global__ __launch_bounds__(256) void f2b_kernel(const float* __restrict__ in,
                                                  u16* __restrict__ out, int n8) {
  int i = blockIdx.x * 256 + threadIdx.x;
  if (i >= n8) return;
  const f32x4* in4 = (const f32x4*)in;
  f32x4 a = in4[i * 2], b = in4[i * 2 + 1];
  bf8pack p;
  p.v[0] = f2bu(a[0]); p.v[1] = f2bu(a[1]); p.v[2] = f2bu(a[2]); p.v[3] = f2bu(a[3]);
  p.v[4] = f2bu(b[0]); p.v[5] = f2bu(b[1]); p.v[6] = f2bu(b[2]); p.v[7] = f2bu(b[3]);
  ((bf8pack*)out)[i] = p;
}

// ---------------- fp32 W[N][1024] -> [hi|hi|lo] bf16 [N][3072] (B-side split) ----------------
__global__ __launch_bounds__(256) void wsplit3_kernel(const float* __restrict__ w,
                                                      u16* __restrict__ out) {
  int i = blockIdx.x * 256 + threadIdx.x;  // 8-elem group
  int n = i >> 7, k0 = (i & 127) * 8;
  const f32x4* p = (const f32x4*)(w + (size_t)n * 1024 + k0);
  f32x4 a = p[0], b = p[1];
  float f[8] = {a[0], a[1], a[2], a[3], b[0], b[1], b[2], b[3]};
  bf8pack hi, lo;
#pragma unroll
  for (int t = 0; t < 8; ++t) {
    hi.v[t] = f2bu(f[t]);
    lo.v[t] = f2bu(f[t] - bu2f(hi.v[t]));
  }
  u16* o = out + (size_t)n * 3072 + k0;
  *(bf8pack*)o = hi;
  *(bf8pack*)(o + 1024) = hi;
  *(bf8pack*)(o + 2048) = lo;
}

// ---------------- fp32 A[4096][1024] -> [hi|lo|hi] bf16 [4096][3072] (A-side split) ----------------
__global__ __launch_bounds__(256) void asplit3_kernel(const float* __restrict__ a,
                                                      u16* __restrict__ out) {
  int i = blockIdx.x * 256 + threadIdx.x;
  int n = i >> 7, k0 = (i & 127) * 8;
  const f32x4* p = (const f32x4*)(a + (size_t)n * 1024 + k0);
  f32x4 x = p[0], y = p[1];
  float f[8] = {x[0], x[1], x[2], x[3], y[0], y[1], y[2], y[3]};
  bf8pack hi, lo;
#pragma unroll
  for (int t = 0; t < 8; ++t) {
    hi.v[t] = f2bu(f[t]);
    lo.v[t] = f2bu(f[t] - bu2f(hi.v[t]));
  }
  u16* o = out + (size_t)n * 3072 + k0;
  *(bf8pack*)o = hi;
  *(bf8pack*)(o + 1024) = lo;
  *(bf8pack*)(o + 2048) = hi;
}

// ---------------- RMSNorm fp32 row(1024) -> [hi|lo|hi] bf16 row(3072) ----------------
__global__ __launch_bounds__(256) void rmsnorm3_kernel(const float* __restrict__ x,
                                                       const float* __restrict__ w,
                                                       u16* __restrict__ out) {
  int row = blockIdx.x;
  int tid = threadIdx.x;
  const f32x4* xr = (const f32x4*)(x + (size_t)row * 1024);
  f32x4 v = xr[tid];
  float ss = v[0] * v[0] + v[1] * v[1] + v[2] * v[2] + v[3] * v[3];
#pragma unroll
  for (int off = 32; off; off >>= 1) ss += __shfl_xor(ss, off);
  __shared__ float part[4];
  if ((tid & 63) == 0) part[tid >> 6] = ss;
  __syncthreads();
  float rs = rsqrtf((part[0] + part[1] + part[2] + part[3]) * (1.0f / 1024.0f) + 1e-6f);
  const f32x4* w4 = (const f32x4*)w;
  f32x4 wv = w4[tid];
  float f[4] = {v[0] * rs * wv[0], v[1] * rs * wv[1], v[2] * rs * wv[2], v[3] * rs * wv[3]};
  bf4pack hi, lo;
#pragma unroll
  for (int t = 0; t < 4; ++t) {
    hi.v[t] = f2bu(f[t]);
    lo.v[t] = f2bu(f[t] - bu2f(hi.v[t]));
  }
  u16* o = out + (size_t)row * 3072;
  ((bf4pack*)o)[tid] = hi;
  ((bf4pack*)(o + 1024))[tid] = lo;
  ((bf4pack*)(o + 2048))[tid] = hi;
}

// ---------------- RMSNorm: fp32 row(1024) -> bf16 (MoE input, single-term) ----------------
__global__ __launch_bounds__(256) void rmsnorm_kernel(const float* __restrict__ x,
                                                      const float* __restrict__ w,
                                                      u16* __restrict__ out) {
  int row = blockIdx.x;
  int tid = threadIdx.x;
  const f32x4* xr = (const f32x4*)(x + (size_t)row * 1024);
  f32x4 v = xr[tid];
  float ss = v[0] * v[0] + v[1] * v[1] + v[2] * v[2] + v[3] * v[3];
#pragma unroll
  for (int off = 32; off; off >>= 1) ss += __shfl_xor(ss, off);
  __shared__ float part[4];
  if ((tid & 63) == 0) part[tid >> 6] = ss;
  __syncthreads();
  float rs = rsqrtf((part[0] + part[1] + part[2] + part[3]) * (1.0f / 1024.0f) + 1e-6f);
  const f32x4* w4 = (const f32x4*)w;
  f32x4 wv = w4[tid];
  bf4pack o;
  o.v[0] = f2bu(v[0] * rs * wv[0]);
  o.v[1] = f2bu(v[1] * rs * wv[1]);
  o.v[2] = f2bu(v[2] * rs * wv[2]);
  o.v[3] = f2bu(v[3] * rs * wv[3]);
  ((bf4pack*)out)[(size_t)row * 256 + tid] = o;
}

// ---------------- MFMA GEMM, C = A @ B^T, 128x128 tile, BK=64, 4 waves ----------------
// MODE 0: C f32  = acc + bias                       (qkv, split-K input)
// MODE 1: C f32  = acc + bias + resid               (out-proj + residual, split-K input)
// MODE 2: gathered A (slot_token), dual B, h = silu(acc1+b1)*(acc2+b2) -> bf16
// MODE 3: scatter: atomicAdd(out[token], (acc+bias)*slot_weight)
template <int MODE>
__global__ __launch_bounds__(256, 2) void gemm_kernel(
    const u16* __restrict__ A, const u16* __restrict__ B1g, const u16* __restrict__ B2g,
    const float* __restrict__ bias1, const float* __restrict__ bias2,
    void* __restrict__ outp, const float* __restrict__ resid, int N, int K,
    const int* __restrict__ counts, const int* __restrict__ opad,
    const int* __restrict__ slot_token, const float* __restrict__ slot_weight) {
  constexpr bool DUAL = (MODE == 2);
  const int tid = threadIdx.x;
  const int lane = tid & 63;
  const int wid = tid >> 6;
  const int wr = wid >> 1, wc = wid & 1;
  const int n0 = blockIdx.x * 128;
  const int mt = blockIdx.y;
  const int e = (MODE >= 2) ? blockIdx.z : 0;
  int m0;
  if (MODE >= 2) {
    int cnt = counts[e];
    if (mt * 128 >= cnt) return;
    m0 = opad[e] + mt * 128;
  } else {
    m0 = mt * 128;
  }
  const u16* B1 = B1g + ((MODE >= 2) ? (size_t)e * (size_t)N * (size_t)K : (size_t)0);
  const u16* B2 = DUAL ? (B2g + (size_t)e * (size_t)N * (size_t)K) : nullptr;
  const float* bb1 = bias1 + ((MODE >= 2) ? e * N : 0);
  const float* bb2 = DUAL ? (bias2 + e * N) : nullptr;

  __shared__ u16 smem[(DUAL ? 3 : 2) * 128 * 64];
  u16* As = smem;
  u16* Bs = smem + 128 * 64;
  u16* B2s = smem + 2 * 128 * 64;

  const f32x4 zero4 = {0.f, 0.f, 0.f, 0.f};
  f32x4 acc[4][4], acc2[4][4];
#pragma unroll
  for (int mi = 0; mi < 4; ++mi)
#pragma unroll
    for (int ni = 0; ni < 4; ++ni) {
      acc[mi][ni] = zero4;
      if constexpr (DUAL) acc2[mi][ni] = zero4;
    }

  const int rsel = lane & 15;
  const int ksel = lane >> 4;

  for (int k0 = 0; k0 < K; k0 += 64) {
    if (k0) __syncthreads();
#pragma unroll
    for (int i = 0; i < 4; ++i) {
      int c = tid + i * 256;
      int row = c >> 3;
      int col = (c & 7) * 8;
      size_t arow;
      if constexpr (MODE == 2) arow = (size_t)slot_token[m0 + row];
      else arow = (size_t)(m0 + row);
      gl_lds16(A + arow * (size_t)K + k0 + col, As + c * 8);
      gl_lds16(B1 + (size_t)(n0 + row) * K + k0 + col, Bs + c * 8);
      if constexpr (DUAL) gl_lds16(B2 + (size_t)(n0 + row) * K + k0 + col, B2s + c * 8);
    }
    __syncthreads();
    const u16* Aw = As + (wr * 64) * 64;
    const u16* Bw = Bs + (wc * 64) * 64;
    const u16* B2w = B2s + (wc * 64) * 64;
#pragma unroll
    for (int ks = 0; ks < 2; ++ks) {
      int ko = ks * 32 + ksel * 8;
      bf16x8 a[4], b[4];
#pragma unroll
      for (int mi = 0; mi < 4; ++mi) a[mi] = *(const bf16x8*)(Aw + (mi * 16 + rsel) * 64 + ko);
#pragma unroll
      for (int ni = 0; ni < 4; ++ni) b[ni] = *(const bf16x8*)(Bw + (ni * 16 + rsel) * 64 + ko);
#pragma unroll
      for (int mi = 0; mi < 4; ++mi)
#pragma unroll
        for (int ni = 0; ni < 4; ++ni) acc[mi][ni] = MFMA16(a[mi], b[ni], acc[mi][ni]);
      if constexpr (DUAL) {
        bf16x8 b2[4];
#pragma unroll
        for (int ni = 0; ni < 4; ++ni) b2[ni] = *(const bf16x8*)(B2w + (ni * 16 + rsel) * 64 + ko);
#pragma unroll
        for (int mi = 0; mi < 4; ++mi)
#pragma unroll
          for (int ni = 0; ni < 4; ++ni) acc2[mi][ni] = MFMA16(a[mi], b2[ni], acc2[mi][ni]);
      }
    }
  }

  // epilogue: C row = (lane>>4)*4 + j, col = lane&15  [m89-verified layout]
#pragma unroll
  for (int mi = 0; mi < 4; ++mi) {
#pragma unroll
    for (int j = 0; j < 4; ++j) {
      int gm = m0 + wr * 64 + mi * 16 + ksel * 4 + j;
#pragma unroll
      for (int ni = 0; ni < 4; ++ni) {
        int gn = n0 + wc * 64 + ni * 16 + rsel;
        float v = acc[mi][ni][j];
        if constexpr (MODE == 0) {
          ((float*)outp)[(size_t)gm * N + gn] = v + bb1[gn];
        } else if constexpr (MODE == 1) {
          ((float*)outp)[(size_t)gm * N + gn] = v + bb1[gn] + resid[(size_t)gm * N + gn];
        } else if constexpr (MODE == 2) {
          float v1 = v + bb1[gn];
          float v2 = acc2[mi][ni][j] + bb2[gn];
          float hv = (v1 / (1.f + __expf(-v1))) * v2;  // silu(v1)*v2
          ((u16*)outp)[(size_t)gm * N + gn] = f2bu(hv);
        } else {
          int tok = slot_token[gm];
          float w = slot_weight[gm];
          atomicAdd(((float*)outp) + (size_t)tok * N + gn, (v + bb1[gn]) * w);
        }
      }
    }
  }
}

// ---------------- RoPE (double-precision angles) + split qkv -> hi/lo planes ----------------
__global__ __launch_bounds__(256) void rope_split_kernel(
    const float* __restrict__ qkv, u16* __restrict__ qhp, u16* __restrict__ qlp,
    u16* __restrict__ khp, u16* __restrict__ klp, u16* __restrict__ vhp,
    u16* __restrict__ vlp) {
  int idx = blockIdx.x * 256 + threadIdx.x;  // [bh][s][hd] flat, 4,194,304
  int hd = idx & 63;
  int s = (idx >> 6) & 2047;
  int bh = idx >> 17;
  int b = bh >> 4, h = bh & 15;
  size_t base = (size_t)(b * 2048 + s) * 3072 + (size_t)h * 64;
  float qv = qkv[base + hd];
  float qp = qkv[base + (hd ^ 32)];
  float kv = qkv[base + 1024 + hd];
  float kp = qkv[base + 1024 + (hd ^ 32)];
  float vv = qkv[base + 2048 + hd];
  int j = hd & 31;
  // double-precision angle: fp32 angle has ulp ~1.2e-4 at s=2047 -> would flip routing
  double invf = exp((double)j * (-9.210340371976184 / 32.0));  // 10000^(-j/32)
  double ang = (double)s * invf;
  const double twopi = 6.283185307179586;
  double r = ang - twopi * floor(ang / twopi);
  float sn, c;
  sincosf((float)r, &sn, &c);
  float qo = (hd < 32) ? (qv * c - qp * sn) : (qv * c + qp * sn);
  float ko = (hd < 32) ? (kv * c - kp * sn) : (kv * c + kp * sn);
  u16 qh = f2bu(qo), kh = f2bu(ko), vh = f2bu(vv);
  qhp[idx] = qh; qlp[idx] = f2bu(qo - bu2f(qh));
  khp[idx] = kh; klp[idx] = f2bu(ko - bu2f(kh));
  vhp[idx] = vh; vlp[idx] = f2bu(vv - bu2f(vh));
}

// ---------------- flash attention, split-precision (hi/lo) Q,K,V,P — swizzled LDS ----------------
__global__ __launch_bounds__(256, 3) void flash_kernel(
    const u16* __restrict__ qhp, const u16* __restrict__ qlp, const u16* __restrict__ khp,
    const u16* __restrict__ klp, const u16* __restrict__ vhp, const u16* __restrict__ vlp,
    float* __restrict__ attn_out) {
  int qblk = blockIdx.x, bh = blockIdx.y;
  int tid = threadIdx.x, lane = tid & 63, wid = tid >> 6;
  const int rsel = lane & 15, ksel = lane >> 4;
  const size_t bhbase = (size_t)bh * 2048 * 64;
  __shared__ u16 Ksh[64 * 64], Ksl[64 * 64];
  __shared__ u16 Vsh[64 * 64], Vsl[64 * 64];  // transposed: [hd][kv], swizzled
  __shared__ u16 Psh[4][16 * 64], Psl[4][16 * 64];
  int qr0 = qblk * 64 + wid * 16;
  bf16x8 qfh[2], qfl[2];
#pragma unroll
  for (int ks = 0; ks < 2; ++ks) {
    size_t qoff = bhbase + (size_t)(qr0 + rsel) * 64 + ks * 32 + ksel * 8;
    qfh[ks] = *(const bf16x8*)(qhp + qoff);
    qfl[ks] = *(const bf16x8*)(qlp + qoff);
  }

  const f32x4 zero4 = {0.f, 0.f, 0.f, 0.f};
  f32x4 po[4];
  float m_i[4], l_i[4];
#pragma unroll
  for (int i = 0; i < 4; ++i) { po[i] = zero4; m_i[i] = -1e30f; l_i[i] = 0.f; }

  for (int kv0 = 0; kv0 < 2048; kv0 += 64) {
    __syncthreads();
#pragma unroll
    for (int i = 0; i < 2; ++i) {  // K tiles: gl_lds with inverse-swizzled per-lane source
      int c = tid + i * 256;
      int srcoff = (c * 8) ^ swz(c >> 3);  // row = c>>3, linear-dest/pre-swz-source
      gl_lds16(khp + bhbase + (size_t)kv0 * 64 + srcoff, Ksh + c * 8);
      gl_lds16(klp + bhbase + (size_t)kv0 * 64 + srcoff, Ksl + c * 8);
    }
#pragma unroll
    for (int i = 0; i < 2; ++i) {  // V tiles transposed, swizzled writes
      int c = tid + i * 256;
      int r = c >> 3, col0 = (c & 7) * 8;
      bf16x8 a = *(const bf16x8*)(vhp + bhbase + (size_t)(kv0 + r) * 64 + col0);
      bf16x8 bl = *(const bf16x8*)(vlp + bhbase + (size_t)(kv0 + r) * 64 + col0);
#pragma unroll
      for (int jj = 0; jj < 8; ++jj) {
        int d = col0 + jj;
        int widx = (d * 64 + r) ^ swz(d);
        Vsh[widx] = (u16)a[jj];
        Vsl[widx] = (u16)bl[jj];
      }
    }
    __syncthreads();

    f32x4 sa[4] = {zero4, zero4, zero4, zero4};
    __builtin_amdgcn_s_setprio(1);
#pragma unroll
    for (int ks = 0; ks < 2; ++ks) {
      int ko = ks * 32 + ksel * 8;
#pragma unroll
      for (int ni = 0; ni < 4; ++ni) {
        int row = ni * 16 + rsel;
        int idx = (row * 64 + ko) ^ swz(row);
        bf16x8 kbh = *(const bf16x8*)(Ksh + idx);
        bf16x8 kbl = *(const bf16x8*)(Ksl + idx);
        sa[ni] = MFMA16(qfh[ks], kbh, sa[ni]);
        sa[ni] = MFMA16(qfl[ks], kbh, sa[ni]);
        sa[ni] = MFMA16(qfh[ks], kbl, sa[ni]);
      }
    }
    __builtin_amdgcn_s_setprio(0);
    const float scale = 0.125f;
    float corr[4];
#pragma unroll
    for (int i = 0; i < 4; ++i) {
      float t = sa[0][i] * scale;
      t = fmaxf(t, sa[1][i] * scale);
      t = fmaxf(t, sa[2][i] * scale);
      t = fmaxf(t, sa[3][i] * scale);
#pragma unroll
      for (int off = 1; off < 16; off <<= 1) t = fmaxf(t, __shfl_xor(t, off));
      float mn = fmaxf(m_i[i], t);
      corr[i] = __expf(m_i[i] - mn);
      m_i[i] = mn;
    }
    float rsum[4] = {0.f, 0.f, 0.f, 0.f};
#pragma unroll
    for (int ni = 0; ni < 4; ++ni)
#pragma unroll
      for (int i = 0; i < 4; ++i) {
        float p = __expf(sa[ni][i] * scale - m_i[i]);
        rsum[i] += p;
        u16 ph = f2bu(p);
        int prow = ksel * 4 + i;
        int pidx = (prow * 64 + ni * 16 + rsel) ^ swz(prow);
        Psh[wid][pidx] = ph;
        Psl[wid][pidx] = f2bu(p - bu2f(ph));
      }
#pragma unroll
    for (int i = 0; i < 4; ++i) {
      float t = rsum[i];
#pragma unroll
      for (int off = 1; off < 16; off <<= 1) t += __shfl_xor(t, off);
      l_i[i] = l_i[i] * corr[i] + t;
    }
#pragma unroll
    for (int nh = 0; nh < 4; ++nh)
#pragma unroll
      for (int i = 0; i < 4; ++i) po[nh][i] *= corr[i];
    __syncthreads();  // P writes visible (safe barrier; drains lgkm)
    __builtin_amdgcn_s_setprio(1);
#pragma unroll
    for (int ks = 0; ks < 2; ++ks) {
      int ko = ks * 32 + ksel * 8;
      int pidx = (rsel * 64 + ko) ^ swz(rsel);
      bf16x8 pfh = *(const bf16x8*)(&Psh[wid][pidx]);
      bf16x8 pfl = *(const bf16x8*)(&Psl[wid][pidx]);
#pragma unroll
      for (int nh = 0; nh < 4; ++nh) {
        int row = nh * 16 + rsel;
        int idx = (row * 64 + ko) ^ swz(row);
        bf16x8 vbh = *(const bf16x8*)(Vsh + idx);
        bf16x8 vbl = *(const bf16x8*)(Vsl + idx);
        po[nh] = MFMA16(pfh, vbh, po[nh]);
        po[nh] = MFMA16(pfl, vbh, po[nh]);
        po[nh] = MFMA16(pfh, vbl, po[nh]);
      }
    }
    __builtin_amdgcn_s_setprio(0);
  }
  int b = bh >> 4, h = bh & 15;
#pragma unroll
  for (int i = 0; i < 4; ++i) {
    float inv = 1.0f / l_i[i];
    int row = qr0 + ksel * 4 + i;
    size_t obase = (size_t)(b * 2048 + row) * 1024 + (size_t)h * 64;
#pragma unroll
    for (int nh = 0; nh < 4; ++nh) attn_out[obase + nh * 16 + rsel] = po[nh][i] * inv;
  }
}

// ---------------- gate: fp32 rmsnorm + logits + top2 (1 wave / token) ----------------
__global__ __launch_bounds__(256) void gate_kernel(const float* __restrict__ xres,
                                                   const float* __restrict__ n2w,
                                                   const float* __restrict__ gw,
                                                   int* __restrict__ tok_e, float* __restrict__ tok_w,
                                                   int* __restrict__ counts) {
  int token = blockIdx.x * 4 + (threadIdx.x >> 6);
  int lane = threadIdx.x & 63;
  const f32x4* xr = (const f32x4*)(xres + (size_t)token * 1024);
  f32x4 xv[4];
  float ss = 0.f;
#pragma unroll
  for (int i = 0; i < 4; ++i) {
    xv[i] = xr[lane * 4 + i];
    ss += xv[i][0] * xv[i][0] + xv[i][1] * xv[i][1] + xv[i][2] * xv[i][2] + xv[i][3] * xv[i][3];
  }
#pragma unroll
  for (int off = 32; off; off >>= 1) ss += __shfl_xor(ss, off);
  float rs = rsqrtf(ss * (1.0f / 1024.0f) + 1e-6f);
  const f32x4* w4 = (const f32x4*)n2w;
#pragma unroll
  for (int i = 0; i < 4; ++i) {
    f32x4 wv = w4[lane * 4 + i];
    xv[i][0] *= rs * wv[0]; xv[i][1] *= rs * wv[1]; xv[i][2] *= rs * wv[2]; xv[i][3] *= rs * wv[3];
  }
  float lg[8];
#pragma unroll
  for (int ee = 0; ee < 8; ++ee) {
    const f32x4* g4 = (const f32x4*)(gw + ee * 1024);
    float a = 0.f;
#pragma unroll
    for (int i = 0; i < 4; ++i) {
      f32x4 g = g4[lane * 4 + i];
      a += xv[i][0] * g[0] + xv[i][1] * g[1] + xv[i][2] * g[2] + xv[i][3] * g[3];
    }
#pragma unroll
    for (int off = 32; off; off >>= 1) a += __shfl_xor(a, off);
    lg[ee] = a;
  }
  if (lane == 0) {
    int i1 = 0; float v1 = lg[0];
#pragma unroll
    for (int ee = 1; ee < 8; ++ee) if (lg[ee] > v1) { v1 = lg[ee]; i1 = ee; }
    int i2 = -1; float v2 = -3e38f;
#pragma unroll
    for (int ee = 0; ee < 8; ++ee) if (ee != i1 && lg[ee] > v2) { v2 = lg[ee]; i2 = ee; }
    float s2 = 1.f / (1.f + __expf(v1 - v2));
    float s1 = 1.f - s2;
    tok_e[token * 2] = i1; tok_e[token * 2 + 1] = i2;
    tok_w[token * 2] = s1; tok_w[token * 2 + 1] = s2;
    atomicAdd(&counts[i1], 1); atomicAdd(&counts[i2], 1);
  }
}

__global__ void init_kernel(int* counts, int* cursor, int* slot_token, float* slot_weight) {
  int i = blockIdx.x * 256 + threadIdx.x;
  if (i < 8) { counts[i] = 0; cursor[i] = 0; }
  if (i < 10240) { slot_token[i] = 0; slot_weight[i] = 0.f; }
}

__global__ void scan_kernel(const int* counts, int* opad) {
  if (threadIdx.x == 0) {
    int off = 0;
    for (int e = 0; e < 8; ++e) { opad[e] = off; off += ((counts[e] + 127) >> 7) << 7; }
  }
}

__global__ __launch_bounds__(256) void assign_kernel(const int* __restrict__ tok_e,
                                                     const float* __restrict__ tok_w,
                                                     const int* __restrict__ opad, int* cursor,
                                                     int* __restrict__ slot_token,
                                                     float* __restrict__ slot_weight) {
  int t = blockIdx.x * 256 + threadIdx.x;
#pragma unroll
  for (int j = 0; j < 2; ++j) {
    int e = tok_e[t * 2 + j];
    int pos = atomicAdd(&cursor[e], 1);
    slot_token[opad[e] + pos] = t;
    slot_weight[opad[e] + pos] = tok_w[t * 2 + j];
  }
}

extern "C" void kernel_launch(void* const* d_in, const int* in_sizes, int n_in, void* d_out,
                              int out_size, void* d_ws, size_t ws_size, hipStream_t stream) {
  const float* x = (const float*)d_in[0];
  const float* n1w = (const float*)d_in[1];
  const float* n2w = (const float*)d_in[2];
  const float* qkv_w = (const float*)d_in[3];
  const float* qkv_b = (const float*)d_in[4];
  const float* out_w = (const float*)d_in[5];
  const float* out_b = (const float*)d_in[6];
  const float* gate_w = (const float*)d_in[7];
  const float* w1 = (const float*)d_in[8];
  const float* b1 = (const float*)d_in[9];
  const float* w2 = (const float*)d_in[10];
  const float* b2 = (const float*)d_in[11];
  const float* w3 = (const float*)d_in[12];
  const float* b3 = (const float*)d_in[13];
  float* out = (float*)d_out;

  const size_t MB = 1024 * 1024;
  char* ws = (char*)d_ws;
  // R0 (96MB): phase1: qkvbuf f32 (48M) + 6 q/k/v planes (8M each); phase2: w1b/w2b/w3b (32M each)
  char* R0 = ws;
  // R1 (44MB): phase1: xn3 (24M) + qkvw3 (18M); then attn3 (24M) overlays xn3; then hbuf (38M)
  char* R1 = ws + 96 * MB;
  // R2 (16MB): attnout f32 (16M); then xn_moe bf16 (8M)
  char* R2 = R1 + 44 * MB;
  // R3 (8MB): outw3 (6M)
  char* R3 = R2 + 16 * MB;
  // R4 (1MB): routing metadata
  char* R4 = R3 + 8 * MB;
  if ((size_t)(165 * MB) > ws_size) return;  // signature: absmax == max|ref|

  float* qkvbuf = (float*)R0;
  u16* qhp = (u16*)(R0 + 48 * MB);
  u16* qlp = (u16*)(R0 + 56 * MB);
  u16* khp = (u16*)(R0 + 64 * MB);
  u16* klp = (u16*)(R0 + 72 * MB);
  u16* vhp = (u16*)(R0 + 80 * MB);
  u16* vlp = (u16*)(R0 + 88 * MB);
  u16* w1b = (u16*)R0;
  u16* w2b = (u16*)(R0 + 32 * MB);
  u16* w3b = (u16*)(R0 + 64 * MB);
  u16* xn3 = (u16*)R1;
  u16* qkvw3 = (u16*)(R1 + 24 * MB);
  u16* attn3 = (u16*)R1;
  u16* hbuf = (u16*)R1;
  float* attnout = (float*)R2;
  u16* xn_moe = (u16*)R2;
  u16* outw3 = (u16*)R3;
  int* tok_e = (int*)R4;
  float* tok_w = (float*)(R4 + 64 * 1024);
  int* counts = (int*)(R4 + 128 * 1024);
  int* cursor = (int*)(R4 + 132 * 1024);
  int* opad = (int*)(R4 + 136 * 1024);
  int* slot_token = (int*)(R4 + 192 * 1024);
  float* slot_weight = (float*)(R4 + 256 * 1024);

  // ---- attention path (split precision) ----
  rmsnorm3_kernel<<<4096, 256, 0, stream>>>(x, n1w, xn3);
  wsplit3_kernel<<<1536, 256, 0, stream>>>(qkv_w, qkvw3);
  wsplit3_kernel<<<512, 256, 0, stream>>>(out_w, outw3);
  gemm_kernel<0><<<dim3(24, 32, 1), 256, 0, stream>>>(xn3, qkvw3, nullptr, qkv_b, nullptr, qkvbuf,
                                                      nullptr, 3072, 3072, nullptr, nullptr,
                                                      nullptr, nullptr);
  rope_split_kernel<<<16384, 256, 0, stream>>>(qkvbuf, qhp, qlp, khp, klp, vhp, vlp);
  flash_kernel<<<dim3(32, 32, 1), 256, 0, stream>>>(qhp, qlp, khp, klp, vhp, vlp, attnout);
  // MoE weight converts (R0 planes dead after flash)
  f2b_kernel<<<8192, 256, 0, stream>>>(w1, w1b, 2097152);
  f2b_kernel<<<8192, 256, 0, stream>>>(w2, w2b, 2097152);
  f2b_kernel<<<8192, 256, 0, stream>>>(w3, w3b, 2097152);
  asplit3_kernel<<<2048, 256, 0, stream>>>(attnout, attn3);
  gemm_kernel<1><<<dim3(8, 32, 1), 256, 0, stream>>>(attn3, outw3, nullptr, out_b, nullptr, out, x,
                                                     1024, 3072, nullptr, nullptr, nullptr, nullptr);
  // ---- MoE path (bf16) ----
  rmsnorm_kernel<<<4096, 256, 0, stream>>>(out, n2w, xn_moe);
  init_kernel<<<40, 256, 0, stream>>>(counts, cursor, slot_token, slot_weight);
  gate_kernel<<<1024, 256, 0, stream>>>(out, n2w, gate_w, tok_e, tok_w, counts);
  scan_kernel<<<1, 64, 0, stream>>>(counts, opad);
  assign_kernel<<<16, 256, 0, stream>>>(tok_e, tok_w, opad, cursor, slot_token, slot_weight);
  gemm_kernel<2><<<dim3(16, 32, 8), 256, 0, stream>>>(xn_moe, w1b, w2b, b1, b2, hbuf, nullptr, 2048,
                                                      1024, counts, opad, slot_token, slot_weight);
  gemm_kernel<3><<<dim3(8, 32, 8), 256, 0, stream>>>(hbuf, w3b, nullptr, b3, nullptr, out, nullptr,
                                                     1024, 2048, counts, opad, slot_token,
                                                     slot_weight);
}